// Round 8
// baseline (31.404 us; speedup 1.0000x reference)
//
#include <hip/hip_runtime.h>
#include <math.h>

// CTC batch cost. Two-kernel pipeline:
//  K1 (1568 blocks): random-gather log2(y_pred[b,t,cls]+eps) -> ws.
//     Block-shared class tables in LDS; threads whose slot is a PADDED label
//     (j in [ll, L)) exit without loading: those lp values provably never
//     reach the output (DP info flows upward in s; output reads s<=2*ll).
//     Cuts gather traffic ~48% on average (ll ~ U[1,48]).
//  K2 (64 blocks x 256): R3/R7-verbatim DP (4-wave stage, wave-0 DP,
//     DPP wave_shr:1, prefetch distance 1).
// Falls back to a fused single kernel if ws_size is too small.

#define NEGV (-1e30f)
#define EPSV (1e-7f)

constexpr int B = 64, T = 128, C = 4000, L = 48;
constexpr int BLANK = C - 1;       // 3999
constexpr int NCLS = L + 1;        // 49: slots 0..47 = labels, 48 = blank
constexpr int TOTAL = B * T * NCLS;  // 401408 = 1568 * 256 exactly

// lane shift up by 1 via DPP wave_shr:1 (VALU latency). Lane 0 gets `old`.
__device__ __forceinline__ float dpp_shr1_neg(float x) {
    int r = __builtin_amdgcn_update_dpp(__float_as_int(NEGV), __float_as_int(x),
                                        0x138 /*wave_shr:1*/, 0xF, 0xF, false);
    return __int_as_float(r);
}

// ---------------- Kernel 1: gather, padded labels skipped ----------------
__global__ __launch_bounds__(256) void gather_kernel(
    const int* __restrict__ y_true,     // [B, L]
    const float* __restrict__ y_pred,   // [B, T, C]
    const int* __restrict__ label_len,  // [B, 1]
    float* __restrict__ lp_ws)          // [B, T, NCLS] log2-probs
{
    const int base = blockIdx.x * 256;
    const int tid  = threadIdx.x;
    const int idx  = base + tid;

    // batch rows covered by this block's 256 indices (at most 2)
    const int b0 = base / (T * NCLS);
    const int b1 = (base + 255) / (T * NCLS);

    __shared__ int cls_s[2 * NCLS];
    __shared__ int ll_sh[2];

    // two different waves build the two tables in parallel
    if (tid < NCLS) {
        int ll = label_len[b0];
        if (tid == 0) ll_sh[0] = ll;
        int cls = BLANK;
        if (tid < L) cls = (tid < ll) ? y_true[b0 * L + tid] : BLANK;
        cls_s[tid] = cls;
    } else if (tid >= 128 && tid < 128 + NCLS) {
        int j = tid - 128;
        int ll = label_len[b1];
        if (j == 0) ll_sh[1] = ll;
        int cls = BLANK;
        if (j < L) cls = (j < ll) ? y_true[b1 * L + j] : BLANK;
        cls_s[NCLS + j] = cls;
    }
    __syncthreads();

    int bt = idx / NCLS;
    int j  = idx - bt * NCLS;
    int b  = bt >> 7;                   // / T
    int rb = b - b0;

    // Padded-label slot: value provably unused by the DP output -> skip.
    if (j >= ll_sh[rb] && j < L) return;

    int cls = cls_s[rb * NCLS + j];
    float p = y_pred[(size_t)bt * C + cls];   // the one HBM-latency hop
    lp_ws[idx] = log2f(p + EPSV);
}

// ---------------- Kernel 2: DP (R3/R7 verbatim) ----------------
__global__ __launch_bounds__(256) void dp_kernel(
    const int* __restrict__ y_true,
    const int* __restrict__ label_len,
    const float* __restrict__ lp_ws,    // [B, T, NCLS]
    float* __restrict__ out)            // [B, 1]
{
    const int b = blockIdx.x;
    const int tid = threadIdx.x;

    __shared__ float lp_s[T * NCLS + 32];
    __shared__ int   lab_s[L];
    __shared__ int   ll_s;

    if (tid < L) {
        int ll = label_len[b];
        if (tid == 0) ll_s = ll;
        int v = y_true[b * L + tid];
        lab_s[tid] = (tid < ll) ? v : BLANK;   // pad with blank as reference
    }

    // coalesced float4 stage: 6272 floats = 1568 float4
    const float4* src = (const float4*)(lp_ws + (size_t)b * T * NCLS);
    float4* dst = (float4*)lp_s;
    for (int i = tid; i < (T * NCLS) / 4; i += 256) dst[i] = src[i];
    __syncthreads();

    if (tid >= 64) return;              // DP on wave 0 only
    const int lane = tid;
    const int ll = ll_s;

    const int myLab   = (lane < L) ? lab_s[lane] : BLANK;
    const int prevLab = (lane >= 1 && lane - 1 < L) ? lab_s[lane - 1] : BLANK;
    const bool allow2 = (lane >= 1) && (myLab != BLANK) && (myLab != prevLab);

    float a0 = (lane == 0) ? lp_s[48] : NEGV;   // t=0, state 0 (blank)
    float a1 = (lane == 0) ? lp_s[0]  : NEGV;   // t=0, state 1 (label 0)

    // prefetch lp for t=1
    float lpb_n = lp_s[1 * NCLS + 48];
    float lpl_n = (lane < L) ? lp_s[1 * NCLS + lane] : 0.0f;

    for (int t = 1; t < T; ++t) {
        float lpb = lpb_n, lpl = lpl_n;
        int tn = (t + 1 < T) ? t + 1 : t;
        lpb_n = lp_s[tn * NCLS + 48];
        lpl_n = (lane < L) ? lp_s[tn * NCLS + lane] : 0.0f;

        float pa1 = dpp_shr1_neg(a1);   // alpha[2l-1] from lane l-1

        // state 2l: lse2(a0, pa1) + lpb
        float m0 = fmaxf(a0, pa1);
        float n0 = fminf(a0, pa1);
        float r0 = (m0 + lpb) + log2f(1.0f + exp2f(n0 - m0));

        // state 2l+1: lse3(a1, a0, allow2 ? pa1 : NEG) + lpl
        float c12 = allow2 ? pa1 : NEGV;
        float m1 = fmaxf(fmaxf(a1, a0), c12);
        float r1 = (m1 + lpl) + log2f(exp2f(a1 - m1) + exp2f(a0 - m1) +
                                      exp2f(c12 - m1));

        a0 = r0;
        a1 = (lane < L) ? r1 : NEGV;    // states beyond S stay dead
    }

    float ab = __shfl(a0, ll);          // alpha[2*ll]
    float al = __shfl(a1, ll - 1);      // alpha[2*ll-1]
    if (lane == 0) {
        float m = fmaxf(ab, al);
        float ll2 = m + log2f(exp2f(ab - m) + exp2f(al - m));
        out[b] = -ll2 * 0.69314718055994531f;   // back to natural log
    }
}

// ---------------- Fallback: fused single kernel (small ws) ----------------
__global__ __launch_bounds__(256) void ctc_fused_kernel(
    const int* __restrict__ y_true,
    const float* __restrict__ y_pred,
    const int* __restrict__ label_len,
    float* __restrict__ out)
{
    const int b = blockIdx.x;
    const int tid = threadIdx.x;

    __shared__ float lp_s[T * NCLS + 32];
    __shared__ int   lab_s[L];
    __shared__ int   ll_s;

    if (tid < L) {
        int ll = label_len[b];
        if (tid == 0) ll_s = ll;
        int v = y_true[b * L + tid];
        lab_s[tid] = (tid < ll) ? v : BLANK;
    }
    __syncthreads();

    const float* yp = y_pred + (size_t)b * T * C;
    for (int g = tid; g < T * NCLS; g += 256) {
        int t = g / NCLS;
        int j = g - t * NCLS;
        int cls = (j < L) ? lab_s[j] : BLANK;
        lp_s[g] = log2f(yp[t * C + cls] + EPSV);
    }
    __syncthreads();

    if (tid >= 64) return;
    const int lane = tid;
    const int ll = ll_s;
    const int myLab   = (lane < L) ? lab_s[lane] : BLANK;
    const int prevLab = (lane >= 1 && lane - 1 < L) ? lab_s[lane - 1] : BLANK;
    const bool allow2 = (lane >= 1) && (myLab != BLANK) && (myLab != prevLab);

    float a0 = (lane == 0) ? lp_s[48] : NEGV;
    float a1 = (lane == 0) ? lp_s[0]  : NEGV;

    for (int t = 1; t < T; ++t) {
        float lpb = lp_s[t * NCLS + 48];
        float lpl = (lane < L) ? lp_s[t * NCLS + lane] : 0.0f;

        float pa1 = dpp_shr1_neg(a1);

        float m0 = fmaxf(a0, pa1);
        float n0 = fminf(a0, pa1);
        float r0 = (m0 + lpb) + log2f(1.0f + exp2f(n0 - m0));

        float c12 = allow2 ? pa1 : NEGV;
        float m1 = fmaxf(fmaxf(a1, a0), c12);
        float r1 = (m1 + lpl) + log2f(exp2f(a1 - m1) + exp2f(a0 - m1) +
                                      exp2f(c12 - m1));

        a0 = r0;
        a1 = (lane < L) ? r1 : NEGV;
    }

    float ab = __shfl(a0, ll);
    float al = __shfl(a1, ll - 1);
    if (lane == 0) {
        float m = fmaxf(ab, al);
        float ll2 = m + log2f(exp2f(ab - m) + exp2f(al - m));
        out[b] = -ll2 * 0.69314718055994531f;
    }
}

extern "C" void kernel_launch(void* const* d_in, const int* in_sizes, int n_in,
                              void* d_out, int out_size, void* d_ws, size_t ws_size,
                              hipStream_t stream) {
    const int*   y_true       = (const int*)d_in[0];
    const float* y_pred       = (const float*)d_in[1];
    const int*   label_length = (const int*)d_in[2];
    float*       out          = (float*)d_out;

    const size_t need = (size_t)TOTAL * sizeof(float);
    if (ws_size >= need) {
        float* lp_ws = (float*)d_ws;
        gather_kernel<<<TOTAL / 256, 256, 0, stream>>>(
            y_true, y_pred, label_length, lp_ws);
        dp_kernel<<<B, 256, 0, stream>>>(y_true, label_length, lp_ws, out);
    } else {
        ctc_fused_kernel<<<B, 256, 0, stream>>>(y_true, y_pred, label_length, out);
    }
}

// Round 9
// 23.080 us; speedup vs baseline: 1.3606x; 1.3606x over previous
//
#include <hip/hip_runtime.h>
#include <math.h>

// CTC batch cost. Two-kernel pipeline:
//  K1 (1568 blocks): random-gather log2(y_pred[b,t,cls]+eps) -> ws.
//     Block-shared class tables in LDS; padded-label slots skipped.
//  K2 (64 blocks x 256): 4-wave stage, wave-0 register DP, DPP wave_shr:1.
//     THIS ROUND: raw v_exp_f32/v_log_f32 via __builtin_amdgcn_* in the
//     dependent chain (no libm range fixups). Operand ranges safe:
//     exp2 args <= 0 (incl -1e30 -> 0), log2 args in [1,3].
// Falls back to a fused single kernel if ws_size is too small.

#define NEGV (-1e30f)
#define EPSV (1e-7f)

constexpr int B = 64, T = 128, C = 4000, L = 48;
constexpr int BLANK = C - 1;       // 3999
constexpr int NCLS = L + 1;        // 49: slots 0..47 = labels, 48 = blank
constexpr int TOTAL = B * T * NCLS;  // 401408 = 1568 * 256 exactly

#if __has_builtin(__builtin_amdgcn_exp2f)
__device__ __forceinline__ float fexp2(float x) { return __builtin_amdgcn_exp2f(x); }
#else
__device__ __forceinline__ float fexp2(float x) { return exp2f(x); }
#endif
#if __has_builtin(__builtin_amdgcn_logf)
__device__ __forceinline__ float flog2(float x) { return __builtin_amdgcn_logf(x); }
#else
__device__ __forceinline__ float flog2(float x) { return log2f(x); }
#endif

// lane shift up by 1 via DPP wave_shr:1 (VALU latency). Lane 0 gets `old`.
__device__ __forceinline__ float dpp_shr1_neg(float x) {
    int r = __builtin_amdgcn_update_dpp(__float_as_int(NEGV), __float_as_int(x),
                                        0x138 /*wave_shr:1*/, 0xF, 0xF, false);
    return __int_as_float(r);
}

// ---------------- Kernel 1: gather, padded labels skipped ----------------
__global__ __launch_bounds__(256) void gather_kernel(
    const int* __restrict__ y_true,     // [B, L]
    const float* __restrict__ y_pred,   // [B, T, C]
    const int* __restrict__ label_len,  // [B, 1]
    float* __restrict__ lp_ws)          // [B, T, NCLS] log2-probs
{
    const int base = blockIdx.x * 256;
    const int tid  = threadIdx.x;
    const int idx  = base + tid;

    // batch rows covered by this block's 256 indices (at most 2)
    const int b0 = base / (T * NCLS);
    const int b1 = (base + 255) / (T * NCLS);

    __shared__ int cls_s[2 * NCLS];
    __shared__ int ll_sh[2];

    // two different waves build the two tables in parallel
    if (tid < NCLS) {
        int ll = label_len[b0];
        if (tid == 0) ll_sh[0] = ll;
        int cls = BLANK;
        if (tid < L) cls = (tid < ll) ? y_true[b0 * L + tid] : BLANK;
        cls_s[tid] = cls;
    } else if (tid >= 128 && tid < 128 + NCLS) {
        int j = tid - 128;
        int ll = label_len[b1];
        if (j == 0) ll_sh[1] = ll;
        int cls = BLANK;
        if (j < L) cls = (j < ll) ? y_true[b1 * L + j] : BLANK;
        cls_s[NCLS + j] = cls;
    }
    __syncthreads();

    int bt = idx / NCLS;
    int j  = idx - bt * NCLS;
    int b  = bt >> 7;                   // / T
    int rb = b - b0;

    // Padded-label slot: value provably unused by the DP output -> skip.
    if (j >= ll_sh[rb] && j < L) return;

    int cls = cls_s[rb * NCLS + j];
    float p = y_pred[(size_t)bt * C + cls];   // the one HBM-latency hop
    lp_ws[idx] = flog2(p + EPSV);
}

// ---------------- Kernel 2: DP ----------------
__global__ __launch_bounds__(256) void dp_kernel(
    const int* __restrict__ y_true,
    const int* __restrict__ label_len,
    const float* __restrict__ lp_ws,    // [B, T, NCLS]
    float* __restrict__ out)            // [B, 1]
{
    const int b = blockIdx.x;
    const int tid = threadIdx.x;

    __shared__ float lp_s[T * NCLS + 32];
    __shared__ int   lab_s[L];
    __shared__ int   ll_s;

    if (tid < L) {
        int ll = label_len[b];
        if (tid == 0) ll_s = ll;
        int v = y_true[b * L + tid];
        lab_s[tid] = (tid < ll) ? v : BLANK;   // pad with blank as reference
    }

    // coalesced float4 stage: 6272 floats = 1568 float4
    const float4* src = (const float4*)(lp_ws + (size_t)b * T * NCLS);
    float4* dst = (float4*)lp_s;
    for (int i = tid; i < (T * NCLS) / 4; i += 256) dst[i] = src[i];
    __syncthreads();

    if (tid >= 64) return;              // DP on wave 0 only
    const int lane = tid;
    const int ll = ll_s;

    const int myLab   = (lane < L) ? lab_s[lane] : BLANK;
    const int prevLab = (lane >= 1 && lane - 1 < L) ? lab_s[lane - 1] : BLANK;
    const bool allow2 = (lane >= 1) && (myLab != BLANK) && (myLab != prevLab);

    float a0 = (lane == 0) ? lp_s[48] : NEGV;   // t=0, state 0 (blank)
    float a1 = (lane == 0) ? lp_s[0]  : NEGV;   // t=0, state 1 (label 0)

    // prefetch lp for t=1
    float lpb_n = lp_s[1 * NCLS + 48];
    float lpl_n = (lane < L) ? lp_s[1 * NCLS + lane] : 0.0f;

    for (int t = 1; t < T; ++t) {
        float lpb = lpb_n, lpl = lpl_n;
        int tn = (t + 1 < T) ? t + 1 : t;
        lpb_n = lp_s[tn * NCLS + 48];
        lpl_n = (lane < L) ? lp_s[tn * NCLS + lane] : 0.0f;

        float pa1 = dpp_shr1_neg(a1);   // alpha[2l-1] from lane l-1

        // state 2l: lse2(a0, pa1) + lpb
        float m0 = fmaxf(a0, pa1);
        float n0 = fminf(a0, pa1);
        float r0 = (m0 + lpb) + flog2(1.0f + fexp2(n0 - m0));

        // state 2l+1: lse3(a1, a0, allow2 ? pa1 : NEG) + lpl
        float c12 = allow2 ? pa1 : NEGV;
        float m1 = fmaxf(fmaxf(a1, a0), c12);
        float r1 = (m1 + lpl) + flog2(fexp2(a1 - m1) + fexp2(a0 - m1) +
                                      fexp2(c12 - m1));

        a0 = r0;
        a1 = (lane < L) ? r1 : NEGV;    // states beyond S stay dead
    }

    float ab = __shfl(a0, ll);          // alpha[2*ll]
    float al = __shfl(a1, ll - 1);      // alpha[2*ll-1]
    if (lane == 0) {
        float m = fmaxf(ab, al);
        float ll2 = m + flog2(fexp2(ab - m) + fexp2(al - m));
        out[b] = -ll2 * 0.69314718055994531f;   // back to natural log
    }
}

// ---------------- Fallback: fused single kernel (small ws) ----------------
__global__ __launch_bounds__(256) void ctc_fused_kernel(
    const int* __restrict__ y_true,
    const float* __restrict__ y_pred,
    const int* __restrict__ label_len,
    float* __restrict__ out)
{
    const int b = blockIdx.x;
    const int tid = threadIdx.x;

    __shared__ float lp_s[T * NCLS + 32];
    __shared__ int   lab_s[L];
    __shared__ int   ll_s;

    if (tid < L) {
        int ll = label_len[b];
        if (tid == 0) ll_s = ll;
        int v = y_true[b * L + tid];
        lab_s[tid] = (tid < ll) ? v : BLANK;
    }
    __syncthreads();

    const float* yp = y_pred + (size_t)b * T * C;
    for (int g = tid; g < T * NCLS; g += 256) {
        int t = g / NCLS;
        int j = g - t * NCLS;
        int cls = (j < L) ? lab_s[j] : BLANK;
        lp_s[g] = flog2(yp[t * C + cls] + EPSV);
    }
    __syncthreads();

    if (tid >= 64) return;
    const int lane = tid;
    const int ll = ll_s;
    const int myLab   = (lane < L) ? lab_s[lane] : BLANK;
    const int prevLab = (lane >= 1 && lane - 1 < L) ? lab_s[lane - 1] : BLANK;
    const bool allow2 = (lane >= 1) && (myLab != BLANK) && (myLab != prevLab);

    float a0 = (lane == 0) ? lp_s[48] : NEGV;
    float a1 = (lane == 0) ? lp_s[0]  : NEGV;

    for (int t = 1; t < T; ++t) {
        float lpb = lp_s[t * NCLS + 48];
        float lpl = (lane < L) ? lp_s[t * NCLS + lane] : 0.0f;

        float pa1 = dpp_shr1_neg(a1);

        float m0 = fmaxf(a0, pa1);
        float n0 = fminf(a0, pa1);
        float r0 = (m0 + lpb) + flog2(1.0f + fexp2(n0 - m0));

        float c12 = allow2 ? pa1 : NEGV;
        float m1 = fmaxf(fmaxf(a1, a0), c12);
        float r1 = (m1 + lpl) + flog2(fexp2(a1 - m1) + fexp2(a0 - m1) +
                                      fexp2(c12 - m1));

        a0 = r0;
        a1 = (lane < L) ? r1 : NEGV;
    }

    float ab = __shfl(a0, ll);
    float al = __shfl(a1, ll - 1);
    if (lane == 0) {
        float m = fmaxf(ab, al);
        float ll2 = m + flog2(fexp2(ab - m) + fexp2(al - m));
        out[b] = -ll2 * 0.69314718055994531f;
    }
}

extern "C" void kernel_launch(void* const* d_in, const int* in_sizes, int n_in,
                              void* d_out, int out_size, void* d_ws, size_t ws_size,
                              hipStream_t stream) {
    const int*   y_true       = (const int*)d_in[0];
    const float* y_pred       = (const float*)d_in[1];
    const int*   label_length = (const int*)d_in[2];
    float*       out          = (float*)d_out;

    const size_t need = (size_t)TOTAL * sizeof(float);
    if (ws_size >= need) {
        float* lp_ws = (float*)d_ws;
        gather_kernel<<<TOTAL / 256, 256, 0, stream>>>(
            y_true, y_pred, label_length, lp_ws);
        dp_kernel<<<B, 256, 0, stream>>>(y_true, label_length, lp_ws, out);
    } else {
        ctc_fused_kernel<<<B, 256, 0, stream>>>(y_true, y_pred, label_length, out);
    }
}